// Round 2
// baseline (20921.085 us; speedup 1.0000x reference)
//
#include <hip/hip_runtime.h>
#include <math.h>

#define NT 1024

__device__ __forceinline__ float sigf(float x)   { return 1.0f / (1.0f + __expf(-x)); }
__device__ __forceinline__ float tanhf_(float x) { return 1.0f - 2.0f / (1.0f + __expf(2.0f * x)); }

__device__ __forceinline__ float dot4(float4 a, float4 b) {
    return a.x * b.x + a.y * b.y + a.z * b.z + a.w * b.w;
}
__device__ __forceinline__ float red16(float v) {
    v += __shfl_xor(v, 1); v += __shfl_xor(v, 2);
    v += __shfl_xor(v, 4); v += __shfl_xor(v, 8);
    return v;
}

// ---------------- v2 GEMV: 8 lanes/row, i-outer, PR rows per lane-group ----
// Rows covered: (w*8+sr) in [0,128) times PR. K = SF4*4*8 floats.
// Per i: 1 LDS broadcast read + PR independent global dwordx4 loads.
template<int SF4, int RS4, int PR, bool BIAS>
__device__ __forceinline__ void gemv8(const float4* __restrict__ W,
                                      const float* __restrict__ act,
                                      const float* __restrict__ bias,
                                      float* __restrict__ outv, int tid) {
    const int l = tid & 63, w = tid >> 6;
    const int q = l & 7, sr = l >> 3;
    const int r0 = (w * 8 + sr) * PR;
    const float4* act4 = (const float4*)act;
    const float4* base = W + (size_t)r0 * RS4 + q * SF4;
    float acc[PR];
    #pragma unroll
    for (int p = 0; p < PR; ++p) acc[p] = 0.f;
    #pragma unroll 1
    for (int i = 0; i < SF4; ++i) {
        float4 a = act4[q * SF4 + i];
        #pragma unroll
        for (int p = 0; p < PR; ++p) acc[p] += dot4(base[(size_t)p * RS4 + i], a);
    }
    #pragma unroll
    for (int p = 0; p < PR; ++p) {
        float v = acc[p];
        v += __shfl_xor(v, 1); v += __shfl_xor(v, 2); v += __shfl_xor(v, 4);
        if (q == 0) {
            if (BIAS) outv[r0 + p] = v + bias[r0 + p];
            else      outv[r0 + p] = v;
        }
    }
}

// ---------------- v2 kernel: one block per batch element --------------------
extern "C" __global__ void __launch_bounds__(NT)
attn_lstm_v2(const float* __restrict__ inp,
             const float* __restrict__ RE0, const float* __restrict__ RE1,
             const float* __restrict__ RD0, const float* __restrict__ RD1,
             const float* __restrict__ bihe, const float* __restrict__ bhhe,
             const float* __restrict__ bihd, const float* __restrict__ bhhd,
             const float* __restrict__ aw1,  const float* __restrict__ ab1,
             const float* __restrict__ aw2,
             const float* __restrict__ dw1,  const float* __restrict__ db1,
             const float* __restrict__ dw2,
             const float* __restrict__ pw,   const float* __restrict__ pb,
             float* __restrict__ out)
{
    extern __shared__ __align__(16) float sm[];
    float* c0     = sm;              // 256
    float* hc1    = sm + 256;        // 512  [h1 | c1]
    float* exL0   = sm + 768;        // 320  [x_in(64) | h0(256)]
    float* g1in   = sm + 1088;       // 512  [h0 | h1]
    float* fullD  = sm + 1600;       // 544  [partial(256)|d_t|0*3|h0(256)|0*28]
    float* gates  = sm + 2144;       // 1024
    float* scoreS = sm + 3168;       // 64
    float* aS     = sm + 3232;       // 64
    float* hctS   = sm + 3296;       // 256
    float* decin  = sm + 3552;       // 64
    float* bE0    = sm + 3616;       // 1024
    float* bE1    = sm + 4640;       // 1024
    float* bD0    = sm + 5664;       // 1024
    float* bD1    = sm + 6688;       // 1024
    float* hexp   = sm + 7712;       // 16384
    float* xeT    = sm + 24096;      // 64*68 = 4352

    const int b   = blockIdx.x;
    const int tid = threadIdx.x;

    // ---- init ----
    for (int i = tid; i < 2144; i += NT) sm[i] = 0.0f;   // c0,hc1,exL0,g1in,fullD
    {
        int j = tid;
        bE0[j] = bihe[j]        + bhhe[j];
        bE1[j] = bihe[1024 + j] + bhhe[1024 + j];
        bD0[j] = bihd[j]        + bhhd[j];
        bD1[j] = bihd[1024 + j] + bhhd[1024 + j];
    }
    const float* ib = inp + b * (64 * 65);
    for (int i = tid; i < 4096; i += NT) {
        int t = i & 63, e = i >> 6;
        xeT[e * 68 + t] = ib[t * 65 + 1 + e];
    }
    if (tid < 64) decin[tid] = ib[tid * 65];
    __syncthreads();

    const int g16 = tid >> 4;   // 0..63
    const int q16 = tid & 15;
    const int wv  = tid >> 6;   // wave 0..15
    const int lq16 = tid & 15;  // lane-in-16 (same as q16)
    const int sr4 = (tid & 63) >> 4;  // 0..3

    // ---- encoder attention P precompute -> regs ----
    float Preg[4], w2r[4];
    #pragma unroll
    for (int jj = 0; jj < 4; ++jj) {
        int j = q16 + 16 * jj;
        w2r[jj] = aw2[j];
        float acc = ab1[j];
        const float4* w4 = (const float4*)(aw1 + j * 576 + 512);
        const float4* x4 = (const float4*)(xeT + g16 * 68);
        #pragma unroll 4
        for (int k = 0; k < 16; ++k) acc += dot4(w4[k], x4[k]);
        Preg[jj] = acc;
    }

    // ================= encoder =================
    for (int t = 0; t < 64; ++t) {
        // E1: hctS[r] = [h1;c1] . aw1[r,0:512)  (64 rows, 16 lanes/row, f4)
        {
            int r = wv * 4 + sr4;
            const float4* w4 = (const float4*)aw1 + (size_t)r * 144 + lq16 * 8;
            const float4* h4 = (const float4*)hc1 + lq16 * 8;
            float acc = 0.f;
            #pragma unroll
            for (int i = 0; i < 8; ++i) acc += dot4(w4[i], h4[i]);
            acc = red16(acc);
            if (lq16 == 0) hctS[r] = acc;
        }
        __syncthreads();
        // E2: score[e] = sum_j tanh(P + hct) * w2
        {
            float s = 0.f;
            #pragma unroll
            for (int jj = 0; jj < 4; ++jj)
                s += tanhf_(Preg[jj] + hctS[q16 + 16 * jj]) * w2r[jj];
            s = red16(s);
            if (q16 == 0) scoreS[g16] = s;
        }
        __syncthreads();
        // E3: softmax + x_in
        if (tid < 64) {
            float v = scoreS[tid];
            float m = v;
            #pragma unroll
            for (int d = 1; d < 64; d <<= 1) m = fmaxf(m, __shfl_xor(m, d));
            float ex = __expf(v - m);
            float s = ex;
            #pragma unroll
            for (int d = 1; d < 64; d <<= 1) s += __shfl_xor(s, d);
            exL0[tid] = (ex / s) * xeT[tid * 68 + t];
        }
        __syncthreads();
        // E4: layer0 gates  (K=320)
        gemv8<10, 80, 8, true>((const float4*)RE0, exL0, bE0, gates, tid);
        __syncthreads();
        // E5: elementwise layer0
        if (tid < 256) {
            int j = tid;
            float cn = sigf(gates[256 + j]) * c0[j] + sigf(gates[j]) * tanhf_(gates[512 + j]);
            float hn = sigf(gates[768 + j]) * tanhf_(cn);
            c0[j] = cn; exL0[64 + j] = hn; g1in[j] = hn;
        }
        __syncthreads();
        // E6: layer1 gates  (K=512)
        gemv8<16, 128, 8, true>((const float4*)RE1, g1in, bE1, gates, tid);
        __syncthreads();
        // E7: elementwise layer1 + h_expanded
        if (tid < 256) {
            int j = tid;
            float cn = sigf(gates[256 + j]) * hc1[256 + j] + sigf(gates[j]) * tanhf_(gates[512 + j]);
            float hn = sigf(gates[768 + j]) * tanhf_(cn);
            hc1[256 + j] = cn; hc1[j] = hn; g1in[256 + j] = hn;
            hexp[t * 256 + j] = hn;
        }
        __syncthreads();
    }

    // ---- transition: zero recurrent state; Pd precompute -> regs ----
    for (int i = tid; i < 768; i += NT) sm[i] = 0.0f;            // c0, hc1
    for (int i = tid; i < 512; i += NT) g1in[i] = 0.0f;
    float Pdreg[16], w2dr[16];
    #pragma unroll
    for (int jj = 0; jj < 16; ++jj) {
        int j = q16 + 16 * jj;
        w2dr[jj] = dw2[j];
        float acc = db1[j];
        const float4* w4 = (const float4*)(dw1 + j * 768 + 512);
        const float4* x4 = (const float4*)(hexp + g16 * 256);
        #pragma unroll 4
        for (int k = 0; k < 64; ++k) acc += dot4(w4[k], x4[k]);
        Pdreg[jj] = acc;
    }
    __syncthreads();

    // ================= decoder =================
    const int j4 = tid >> 2;
    const int q4 = tid & 3;
    for (int t = 0; t < 64; ++t) {
        // D1: hctS[r] = [h1;c1] . dw1[r,0:512)  (256 rows)
        gemv8<16, 192, 2, false>((const float4*)dw1, hc1, nullptr, hctS, tid);
        __syncthreads();
        // D2: scores
        {
            float s = 0.f;
            #pragma unroll
            for (int jj = 0; jj < 16; ++jj)
                s += tanhf_(Pdreg[jj] + hctS[q16 + 16 * jj]) * w2dr[jj];
            s = red16(s);
            if (q16 == 0) scoreS[g16] = s;
        }
        __syncthreads();
        // D3: softmax -> aS ; stage d_t
        if (tid < 64) {
            float v = scoreS[tid];
            float m = v;
            #pragma unroll
            for (int d = 1; d < 64; d <<= 1) m = fmaxf(m, __shfl_xor(m, d));
            float ex = __expf(v - m);
            float s = ex;
            #pragma unroll
            for (int d = 1; d < 64; d <<= 1) s += __shfl_xor(s, d);
            aS[tid] = ex / s;
            if (tid == 0) fullD[256] = decin[t];
        }
        __syncthreads();
        // D4: partial[h] = sum_t hexp[t][h]*a[t]
        {
            float acc = 0.f;
            #pragma unroll 4
            for (int i = 0; i < 16; ++i) {
                int tt = q4 + 4 * i;
                acc += hexp[tt * 256 + j4] * aS[tt];
            }
            acc += __shfl_xor(acc, 1);
            acc += __shfl_xor(acc, 2);
            if (q4 == 0) fullD[j4] = acc;
        }
        __syncthreads();
        // D5: layer0 gates  (K=544 padded)
        gemv8<17, 136, 8, true>((const float4*)RD0, fullD, bD0, gates, tid);
        __syncthreads();
        // D6: elementwise layer0
        if (tid < 256) {
            int j = tid;
            float cn = sigf(gates[256 + j]) * c0[j] + sigf(gates[j]) * tanhf_(gates[512 + j]);
            float hn = sigf(gates[768 + j]) * tanhf_(cn);
            c0[j] = cn; fullD[260 + j] = hn; g1in[j] = hn;
        }
        __syncthreads();
        // D7: layer1 gates  (K=512)
        gemv8<16, 128, 8, true>((const float4*)RD1, g1in, bD1, gates, tid);
        __syncthreads();
        // D8: elementwise layer1
        if (tid < 256) {
            int j = tid;
            float cn = sigf(gates[256 + j]) * hc1[256 + j] + sigf(gates[j]) * tanhf_(gates[512 + j]);
            float hn = sigf(gates[768 + j]) * tanhf_(cn);
            hc1[256 + j] = cn; hc1[j] = hn; g1in[256 + j] = hn;
        }
        __syncthreads();
    }

    // ---- output ----
    if (tid < 64) {
        float acc = 0.f;
        #pragma unroll
        for (int i = 0; i < 8; ++i) {
            int k = tid + 64 * i;
            float v = (k < 256) ? hc1[k] : fullD[k - 256];
            acc += v * pw[k];
        }
        #pragma unroll
        for (int d = 1; d < 64; d <<= 1) acc += __shfl_xor(acc, d);
        if (tid == 0) out[b] = fabsf(acc + pb[0]);
    }
}

// Repack fused weight rows into ws:
//  RE0 @0       : 1024 x 320  [wihe0(64)   | whhe_l0(256)]
//  RE1 @327680  : 1024 x 512  [wihe1(256)  | whhe_l1(256)]
//  RD0 @851968  : 1024 x 544  [wihd0(257) 0*3 | whhd_l0(256) | 0*28]
//  RD1 @1409024 : 1024 x 512  [wihd1(256)  | whhd_l1(256)]
extern "C" __global__ void repack2_k(const float* __restrict__ wihe0,
                                     const float* __restrict__ whhe,
                                     const float* __restrict__ wihe1,
                                     const float* __restrict__ wihd0,
                                     const float* __restrict__ whhd,
                                     const float* __restrict__ wihd1,
                                     float* __restrict__ ws) {
    int idx = blockIdx.x * blockDim.x + threadIdx.x;
    if (idx < 327680) {
        int j = idx / 320, k = idx - j * 320;
        ws[idx] = (k < 64) ? wihe0[j * 64 + k] : whhe[j * 256 + (k - 64)];
        return;
    }
    idx -= 327680;
    if (idx < 524288) {
        int j = idx / 512, k = idx - j * 512;
        ws[327680 + idx] = (k < 256) ? wihe1[j * 256 + k]
                                     : whhe[262144 + j * 256 + (k - 256)];
        return;
    }
    idx -= 524288;
    if (idx < 557056) {
        int j = idx / 544, k = idx - j * 544;
        float v = 0.f;
        if (k < 257)                 v = wihd0[j * 257 + k];
        else if (k >= 260 && k < 516) v = whhd[j * 256 + (k - 260)];
        ws[851968 + idx] = v;
        return;
    }
    idx -= 557056;
    if (idx < 524288) {
        int j = idx / 512, k = idx - j * 512;
        ws[1409024 + idx] = (k < 256) ? wihd1[j * 256 + k]
                                      : whhd[262144 + j * 256 + (k - 256)];
    }
}

// ======================= v1 fallback (small ws) ============================
extern "C" __global__ void __launch_bounds__(NT)
attn_lstm(const float* __restrict__ inp,
          const float* __restrict__ wihe0, const float* __restrict__ wihe1,
          const float* __restrict__ whhe,  const float* __restrict__ bihe,
          const float* __restrict__ bhhe,
          const float* __restrict__ wihd0, const float* __restrict__ wihd0r,
          const float* __restrict__ wihd1,
          const float* __restrict__ whhd,  const float* __restrict__ bihd,
          const float* __restrict__ bhhd,
          const float* __restrict__ aw1,   const float* __restrict__ ab1,
          const float* __restrict__ aw2,
          const float* __restrict__ dw1,   const float* __restrict__ db1,
          const float* __restrict__ dw2,
          const float* __restrict__ pw,    const float* __restrict__ pb,
          float* __restrict__ out, int use_repack)
{
    extern __shared__ __align__(16) float sm[];
    float* h0     = sm;
    float* c0     = h0 + 256;
    float* hc1    = c0 + 256;
    float* full   = hc1 + 512;
    float* gates  = full + 260;
    float* scoreS = gates + 1024;
    float* aS     = scoreS + 64;
    float* hctS   = aS + 64;
    float* decin  = hctS + 256;
    float* hexp   = decin + 64;
    float* xeT    = hexp + 16384;

    const int b   = blockIdx.x;
    const int tid = threadIdx.x;

    for (int i = tid; i < 1284; i += NT) sm[i] = 0.0f;
    const float* ib = inp + b * (64 * 65);
    for (int i = tid; i < 4096; i += NT) {
        int t = i & 63, e = i >> 6;
        xeT[e * 68 + t] = ib[t * 65 + 1 + e];
    }
    if (tid < 64) decin[tid] = ib[tid * 65];
    __syncthreads();

    const int g16 = tid >> 4;
    const int q16 = tid & 15;

    float Preg[4], w2r[4];
    #pragma unroll
    for (int jj = 0; jj < 4; ++jj) {
        int j = q16 + 16 * jj;
        w2r[jj] = aw2[j];
        float acc = ab1[j];
        const float4* w4 = (const float4*)(aw1 + j * 576 + 512);
        const float4* x4 = (const float4*)(xeT + g16 * 68);
        #pragma unroll 4
        for (int k = 0; k < 16; ++k) acc += dot4(w4[k], x4[k]);
        Preg[jj] = acc;
    }

    for (int t = 0; t < 64; ++t) {
        {
            const float* w = aw1 + g16 * 576;
            float acc = 0.f;
            #pragma unroll 8
            for (int i = 0; i < 32; ++i) {
                int k = q16 + 16 * i;
                acc += hc1[k] * w[k];
            }
            acc = red16(acc);
            if (q16 == 0) hctS[g16] = acc;
        }
        __syncthreads();
        {
            float s = 0.f;
            #pragma unroll
            for (int jj = 0; jj < 4; ++jj)
                s += tanhf_(Preg[jj] + hctS[q16 + 16 * jj]) * w2r[jj];
            s = red16(s);
            if (q16 == 0) scoreS[g16] = s;
        }
        __syncthreads();
        if (tid < 64) {
            float v = scoreS[tid];
            float m = v;
            #pragma unroll
            for (int d = 1; d < 64; d <<= 1) m = fmaxf(m, __shfl_xor(m, d));
            float ex = __expf(v - m);
            float s = ex;
            #pragma unroll
            for (int d = 1; d < 64; d <<= 1) s += __shfl_xor(s, d);
            full[tid] = (ex / s) * xeT[tid * 68 + t];
        }
        __syncthreads();
        {
            int j = tid;
            float acc = bihe[j] + bhhe[j];
            const float4* wi = (const float4*)(wihe0 + (j << 6));
            const float4* xf = (const float4*)full;
            #pragma unroll 4
            for (int k = 0; k < 16; ++k) acc += dot4(wi[k], xf[k]);
            const float4* wh = (const float4*)(whhe + (j << 8));
            const float4* h4 = (const float4*)h0;
            #pragma unroll 4
            for (int k = 0; k < 64; ++k) acc += dot4(wh[k], h4[k]);
            gates[j] = acc;
        }
        __syncthreads();
        if (tid < 256) {
            int j = tid;
            float cn = sigf(gates[256 + j]) * c0[j] + sigf(gates[j]) * tanhf_(gates[512 + j]);
            float hn = sigf(gates[768 + j]) * tanhf_(cn);
            c0[j] = cn; h0[j] = hn;
        }
        __syncthreads();
        {
            int j = tid;
            float acc = bihe[1024 + j] + bhhe[1024 + j];
            const float4* wi = (const float4*)(wihe1 + (j << 8));
            const float4* h4 = (const float4*)h0;
            #pragma unroll 4
            for (int k = 0; k < 64; ++k) acc += dot4(wi[k], h4[k]);
            const float4* wh = (const float4*)(whhe + 262144 + (j << 8));
            const float4* h14 = (const float4*)hc1;
            #pragma unroll 4
            for (int k = 0; k < 64; ++k) acc += dot4(wh[k], h14[k]);
            gates[j] = acc;
        }
        __syncthreads();
        if (tid < 256) {
            int j = tid;
            float cn = sigf(gates[256 + j]) * hc1[256 + j] + sigf(gates[j]) * tanhf_(gates[512 + j]);
            float hn = sigf(gates[768 + j]) * tanhf_(cn);
            hc1[256 + j] = cn; hc1[j] = hn;
            hexp[t * 256 + j] = hn;
        }
        __syncthreads();
    }

    sm[tid] = 0.0f;
    float Pdreg[16], w2dr[16];
    #pragma unroll
    for (int jj = 0; jj < 16; ++jj) {
        int j = q16 + 16 * jj;
        w2dr[jj] = dw2[j];
        float acc = db1[j];
        const float4* w4 = (const float4*)(dw1 + j * 768 + 512);
        const float4* x4 = (const float4*)(hexp + g16 * 256);
        #pragma unroll 4
        for (int k = 0; k < 64; ++k) acc += dot4(w4[k], x4[k]);
        Pdreg[jj] = acc;
    }
    __syncthreads();

    const int j4 = tid >> 2;
    const int q4 = tid & 3;
    for (int t = 0; t < 64; ++t) {
        {
            const float4* w4 = (const float4*)(dw1 + j4 * 768 + q4 * 128);
            const float4* x4 = (const float4*)(hc1 + q4 * 128);
            float acc = 0.f;
            #pragma unroll 4
            for (int i = 0; i < 32; ++i) acc += dot4(w4[i], x4[i]);
            acc += __shfl_xor(acc, 1);
            acc += __shfl_xor(acc, 2);
            if (q4 == 0) hctS[j4] = acc;
        }
        __syncthreads();
        {
            float s = 0.f;
            #pragma unroll
            for (int jj = 0; jj < 16; ++jj)
                s += tanhf_(Pdreg[jj] + hctS[q16 + 16 * jj]) * w2dr[jj];
            s = red16(s);
            if (q16 == 0) scoreS[g16] = s;
        }
        __syncthreads();
        if (tid < 64) {
            float v = scoreS[tid];
            float m = v;
            #pragma unroll
            for (int d = 1; d < 64; d <<= 1) m = fmaxf(m, __shfl_xor(m, d));
            float ex = __expf(v - m);
            float s = ex;
            #pragma unroll
            for (int d = 1; d < 64; d <<= 1) s += __shfl_xor(s, d);
            aS[tid] = ex / s;
            if (tid == 0) full[256] = decin[t];
        }
        __syncthreads();
        {
            float acc = 0.f;
            #pragma unroll 4
            for (int i = 0; i < 16; ++i) {
                int tt = q4 + 4 * i;
                acc += hexp[tt * 256 + j4] * aS[tt];
            }
            acc += __shfl_xor(acc, 1);
            acc += __shfl_xor(acc, 2);
            if (q4 == 0) full[j4] = acc;
        }
        __syncthreads();
        {
            int j = tid;
            float acc = bihd[j] + bhhd[j];
            if (use_repack) {
                const float4* wi = (const float4*)(wihd0r + j * 260);
                const float4* xf = (const float4*)full;
                #pragma unroll 5
                for (int k = 0; k < 65; ++k) acc += dot4(wi[k], xf[k]);
            } else {
                const float* wi = wihd0 + j * 257;
                #pragma unroll 8
                for (int k = 0; k < 257; ++k) acc += wi[k] * full[k];
            }
            const float4* wh = (const float4*)(whhd + (j << 8));
            const float4* h4 = (const float4*)h0;
            #pragma unroll 4
            for (int k = 0; k < 64; ++k) acc += dot4(wh[k], h4[k]);
            gates[j] = acc;
        }
        __syncthreads();
        if (tid < 256) {
            int j = tid;
            float cn = sigf(gates[256 + j]) * c0[j] + sigf(gates[j]) * tanhf_(gates[512 + j]);
            float hn = sigf(gates[768 + j]) * tanhf_(cn);
            c0[j] = cn; h0[j] = hn;
        }
        __syncthreads();
        {
            int j = tid;
            float acc = bihd[1024 + j] + bhhd[1024 + j];
            const float4* wi = (const float4*)(wihd1 + (j << 8));
            const float4* h4 = (const float4*)h0;
            #pragma unroll 4
            for (int k = 0; k < 64; ++k) acc += dot4(wi[k], h4[k]);
            const float4* wh = (const float4*)(whhd + 262144 + (j << 8));
            const float4* h14 = (const float4*)hc1;
            #pragma unroll 4
            for (int k = 0; k < 64; ++k) acc += dot4(wh[k], h14[k]);
            gates[j] = acc;
        }
        __syncthreads();
        if (tid < 256) {
            int j = tid;
            float cn = sigf(gates[256 + j]) * hc1[256 + j] + sigf(gates[j]) * tanhf_(gates[512 + j]);
            float hn = sigf(gates[768 + j]) * tanhf_(cn);
            hc1[256 + j] = cn; hc1[j] = hn;
        }
        __syncthreads();
    }

    if (tid < 64) {
        float acc = 0.f;
        #pragma unroll
        for (int i = 0; i < 8; ++i) {
            int k = tid + 64 * i;
            float v = (k < 256) ? hc1[k] : full[k - 256];
            acc += v * pw[k];
        }
        #pragma unroll
        for (int d = 1; d < 64; d <<= 1) acc += __shfl_xor(acc, d);
        if (tid == 0) out[b] = fabsf(acc + pb[0]);
    }
}

extern "C" __global__ void repack_k(const float* __restrict__ src, float* __restrict__ dst) {
    int idx = blockIdx.x * blockDim.x + threadIdx.x;
    if (idx >= 1024 * 260) return;
    int j = idx / 260;
    int k = idx - j * 260;
    dst[idx] = (k < 257) ? src[j * 257 + k] : 0.0f;
}

extern "C" void kernel_launch(void* const* d_in, const int* in_sizes, int n_in,
                              void* d_out, int out_size, void* d_ws, size_t ws_size,
                              hipStream_t stream) {
    const float* inp   = (const float*)d_in[0];
    const float* wihe0 = (const float*)d_in[1];
    const float* wihe1 = (const float*)d_in[2];
    const float* whhe  = (const float*)d_in[3];
    const float* bihe  = (const float*)d_in[4];
    const float* bhhe  = (const float*)d_in[5];
    const float* wihd0 = (const float*)d_in[6];
    const float* wihd1 = (const float*)d_in[7];
    const float* whhd  = (const float*)d_in[8];
    const float* bihd  = (const float*)d_in[9];
    const float* bhhd  = (const float*)d_in[10];
    const float* aw1   = (const float*)d_in[11];
    const float* ab1   = (const float*)d_in[12];
    const float* aw2   = (const float*)d_in[13];
    const float* dw1   = (const float*)d_in[14];
    const float* db1   = (const float*)d_in[15];
    const float* dw2   = (const float*)d_in[16];
    const float* pw    = (const float*)d_in[17];
    const float* pb    = (const float*)d_in[18];
    float* out = (float*)d_out;

    const size_t v2_bytes = (size_t)1933312 * sizeof(float);  // 7.74 MB
    if (ws_size >= v2_bytes) {
        float* ws = (float*)d_ws;
        repack2_k<<<(1933312 + 255) / 256, 256, 0, stream>>>(
            wihe0, whhe, wihe1, wihd0, whhd, wihd1, ws);
        const int smem2 = 28448 * sizeof(float);  // ~114 KB
        hipFuncSetAttribute((const void*)attn_lstm_v2,
                            hipFuncAttributeMaxDynamicSharedMemorySize, smem2);
        attn_lstm_v2<<<64, NT, smem2, stream>>>(
            inp,
            ws, ws + 327680, ws + 851968, ws + 1409024,
            bihe, bhhe, bihd, bhhd,
            aw1, ab1, aw2, dw1, db1, dw2, pw, pb, out);
        return;
    }

    // fallback: v1
    const size_t repack_bytes = (size_t)1024 * 260 * sizeof(float);
    const int use_repack = (ws_size >= repack_bytes) ? 1 : 0;
    float* wr = (float*)d_ws;
    if (use_repack)
        repack_k<<<(1024 * 260 + 255) / 256, 256, 0, stream>>>(wihd0, wr);
    const int smem_bytes = 23492 * sizeof(float);
    hipFuncSetAttribute((const void*)attn_lstm,
                        hipFuncAttributeMaxDynamicSharedMemorySize, smem_bytes);
    attn_lstm<<<64, NT, smem_bytes, stream>>>(
        inp, wihe0, wihe1, whhe, bihe, bhhe,
        wihd0, use_repack ? wr : wihd0, wihd1, whhd, bihd, bhhd,
        aw1, ab1, aw2, dw1, db1, dw2, pw, pb, out, use_repack);
}